// Round 5
// baseline (160.225 us; speedup 1.0000x reference)
//
#include <hip/hip_runtime.h>

#define NN 10000
#define NE 640000
#define NB 313          // buckets of 32 nodes; also # partition blocks (EPB*313 >= NE)
#define RSTRIDE 2688    // slots per bucket (mean 2045, sigma~45)
#define EPB 2048        // edges per partition block
#define G1B 1250        // gemm1 blocks (10000/8)

__device__ __forceinline__ unsigned short f2bf(float x) {   // RNE
    unsigned u = __float_as_uint(x);
    u += 0x7FFFu + ((u >> 16) & 1u);
    return (unsigned short)(u >> 16);
}
__device__ __forceinline__ float bflo(unsigned u) { return __uint_as_float(u << 16); }
__device__ __forceinline__ float bfhi(unsigned u) { return __uint_as_float(u & 0xFFFF0000u); }
__device__ __forceinline__ float bf1(unsigned short h) { return __uint_as_float((unsigned)h << 16); }

__global__ void zero_kernel(int* __restrict__ cur) {
    if (threadIdx.x < NB) cur[threadIdx.x] = 0;
}

// blocks [0,NB): partition edges into dst-buckets. rec = (dst<<14)|src.
// blocks [NB, NB+G1B): gemm1  T1[8 rows] = x[8x128] @ W1[128x128] -> bf16
__global__ __launch_bounds__(256) void part_gemm1_kernel(
        const int* __restrict__ src, const int* __restrict__ dst,
        int* __restrict__ bcur, unsigned* __restrict__ edge_part,
        const float* __restrict__ X, const float* __restrict__ W,
        unsigned short* __restrict__ Y) {
    __shared__ union SM {
        struct { int hist[NB]; int scanv[NB + 1]; int gbase[NB]; int lcur[NB];
                 unsigned stage[EPB]; } p;
        float xs[8][128];
    } sm;
    int tid = threadIdx.x;

    if (blockIdx.x >= NB) {                       // ---- gemm1 path ----
        int row0 = (blockIdx.x - NB) * 8;
        for (int idx = tid; idx < 8 * 128; idx += 256) {
            int r = idx >> 7, k = idx & 127;
            sm.xs[r][k] = X[(size_t)(row0 + r) * 128 + k];
        }
        __syncthreads();
        int ct = tid & 31, r = tid >> 5, c = ct * 4;
        float4 acc = make_float4(0.f, 0.f, 0.f, 0.f);
        #pragma unroll 8
        for (int k = 0; k < 128; ++k) {
            float xv = sm.xs[r][k];
            float4 w = *reinterpret_cast<const float4*>(W + (size_t)k * 128 + c);
            acc.x += xv * w.x; acc.y += xv * w.y; acc.z += xv * w.z; acc.w += xv * w.w;
        }
        ushort4 o;
        o.x = f2bf(acc.x); o.y = f2bf(acc.y); o.z = f2bf(acc.z); o.w = f2bf(acc.w);
        *reinterpret_cast<ushort4*>(Y + (size_t)(row0 + r) * 128 + c) = o;
        return;
    }

    // ---- partition path ----
    for (int i = tid; i < NB; i += 256) sm.p.hist[i] = 0;
    __syncthreads();
    int gi = blockIdx.x * EPB + tid * 8;
    unsigned rec[8];
    bool act = gi < NE;
    if (act) {
        int4 s0 = *reinterpret_cast<const int4*>(src + gi);
        int4 s1 = *reinterpret_cast<const int4*>(src + gi + 4);
        int4 d0 = *reinterpret_cast<const int4*>(dst + gi);
        int4 d1 = *reinterpret_cast<const int4*>(dst + gi + 4);
        rec[0] = ((unsigned)d0.x << 14) | (unsigned)s0.x;
        rec[1] = ((unsigned)d0.y << 14) | (unsigned)s0.y;
        rec[2] = ((unsigned)d0.z << 14) | (unsigned)s0.z;
        rec[3] = ((unsigned)d0.w << 14) | (unsigned)s0.w;
        rec[4] = ((unsigned)d1.x << 14) | (unsigned)s1.x;
        rec[5] = ((unsigned)d1.y << 14) | (unsigned)s1.y;
        rec[6] = ((unsigned)d1.z << 14) | (unsigned)s1.z;
        rec[7] = ((unsigned)d1.w << 14) | (unsigned)s1.w;
        #pragma unroll
        for (int k = 0; k < 8; ++k) atomicAdd(&sm.p.hist[rec[k] >> 19], 1);
    }
    __syncthreads();
    if (tid < 64) {          // wave-0 exclusive scan of hist
        int carry = 0;
        for (int c = 0; c < NB; c += 64) {
            int idx = c + tid;
            int v = (idx < NB) ? sm.p.hist[idx] : 0;
            int incl = v;
            #pragma unroll
            for (int d = 1; d < 64; d <<= 1) {
                int t = __shfl_up(incl, d, 64);
                if (tid >= d) incl += t;
            }
            if (idx < NB) sm.p.scanv[idx] = carry + incl - v;
            carry += __shfl(incl, 63, 64);
        }
        if (tid == 0) sm.p.scanv[NB] = carry;
    }
    __syncthreads();
    for (int b = tid; b < NB; b += 256) {
        sm.p.gbase[b] = atomicAdd(&bcur[b], sm.p.hist[b]);
        sm.p.lcur[b]  = sm.p.scanv[b];
    }
    __syncthreads();
    if (act) {
        #pragma unroll
        for (int k = 0; k < 8; ++k) {
            int b = rec[k] >> 19;
            int p = atomicAdd(&sm.p.lcur[b], 1);
            sm.p.stage[p] = rec[k];
        }
    }
    __syncthreads();
    int tot = sm.p.scanv[NB];
    for (int i = tid; i < tot; i += 256) {
        unsigned r = sm.p.stage[i];
        int b = r >> 19;
        edge_part[b * RSTRIDE + sm.p.gbase[b] + (i - sm.p.scanv[b])] = r;
    }
}

// per bucket: scan totals -> base; degrees -> inv_sqrt/offs; group by node; CSR write
__global__ __launch_bounds__(256) void build_kernel(const unsigned* __restrict__ edge_part,
                                                    const int* __restrict__ bcur,
                                                    int* __restrict__ offs,
                                                    float* __restrict__ inv_sqrt,
                                                    int* __restrict__ edge_src) {
    __shared__ int sbase[NB + 1];
    __shared__ int hist32[32];
    __shared__ int cur32[32];
    __shared__ unsigned stage[RSTRIDE];
    int tid = threadIdx.x;
    if (tid < 64) {
        int carry = 0;
        for (int c = 0; c < NB; c += 64) {
            int idx = c + tid;
            int v = (idx < NB) ? bcur[idx] : 0;
            int incl = v;
            #pragma unroll
            for (int d = 1; d < 64; d <<= 1) {
                int t = __shfl_up(incl, d, 64);
                if (tid >= d) incl += t;
            }
            if (idx < NB) sbase[idx] = carry + incl - v;
            carry += __shfl(incl, 63, 64);
        }
    }
    if (tid < 32) hist32[tid] = 0;
    __syncthreads();
    int b = blockIdx.x;
    int cnt = bcur[b];
    int base = sbase[b];
    const unsigned* part = edge_part + (size_t)b * RSTRIDE;
    for (int k = tid; k < cnt; k += 256)
        atomicAdd(&hist32[(part[k] >> 14) & 31], 1);
    __syncthreads();
    if (tid < 32) {
        int v = hist32[tid];
        int incl = v;
        #pragma unroll
        for (int d = 1; d < 32; d <<= 1) {
            int t = __shfl_up(incl, d, 32);
            if (tid >= d) incl += t;
        }
        int excl = incl - v;
        cur32[tid] = excl;
        int node = b * 32 + tid;
        if (node < NN) {
            offs[node] = base + excl;
            inv_sqrt[node] = rsqrtf((float)(v + 1));
        }
        if (b == NB - 1 && tid == 0) offs[NN] = base + cnt;
    }
    __syncthreads();
    for (int k = tid; k < cnt; k += 256) {
        unsigned r = part[k];
        int p = atomicAdd(&cur32[(r >> 14) & 31], 1);
        stage[p] = r & 0x3FFFu;
    }
    __syncthreads();
    for (int k = tid; k < cnt; k += 256)
        edge_src[base + k] = (int)stage[k];
}

// fused: A = relu(agg(H) + bias) into LDS, then Y = A @ W  (bf16 out)
// H: [NN][128] bf16.  NOUT=128 -> 8 nodes/blk; NOUT=64 -> 16 nodes/blk.
template<int NOUT, int NODES>
__global__ __launch_bounds__(256) void agg_gemm_kernel(
        const unsigned short* __restrict__ H, const int* __restrict__ esrc,
        const int* __restrict__ offs, const float* __restrict__ inv_sqrt,
        const float* __restrict__ bias, const float* __restrict__ W,
        unsigned short* __restrict__ Y) {
    __shared__ float As[NODES][128];
    int tid = threadIdx.x;
    int lane = tid & 63, wv = tid >> 6;
    constexpr int NPW = NODES / 4;
    int col = lane * 2;
    #pragma unroll
    for (int i = 0; i < NPW; ++i) {
        int li = wv * NPW + i;
        int node = blockIdx.x * NODES + li;
        int s = offs[node], e = offs[node + 1];
        float isq = inv_sqrt[node];
        float2 acc = make_float2(0.f, 0.f);
        int j = s;
        for (; j + 4 <= e; j += 4) {
            int s0 = esrc[j], s1 = esrc[j + 1], s2 = esrc[j + 2], s3 = esrc[j + 3];
            float w0 = inv_sqrt[s0], w1 = inv_sqrt[s1];
            float w2 = inv_sqrt[s2], w3 = inv_sqrt[s3];
            unsigned u0 = *reinterpret_cast<const unsigned*>(H + (size_t)s0 * 128 + col);
            unsigned u1 = *reinterpret_cast<const unsigned*>(H + (size_t)s1 * 128 + col);
            unsigned u2 = *reinterpret_cast<const unsigned*>(H + (size_t)s2 * 128 + col);
            unsigned u3 = *reinterpret_cast<const unsigned*>(H + (size_t)s3 * 128 + col);
            acc.x += w0 * bflo(u0); acc.y += w0 * bfhi(u0);
            acc.x += w1 * bflo(u1); acc.y += w1 * bfhi(u1);
            acc.x += w2 * bflo(u2); acc.y += w2 * bfhi(u2);
            acc.x += w3 * bflo(u3); acc.y += w3 * bfhi(u3);
        }
        for (; j < e; ++j) {
            int s0 = esrc[j];
            float w0 = inv_sqrt[s0];
            unsigned u0 = *reinterpret_cast<const unsigned*>(H + (size_t)s0 * 128 + col);
            acc.x += w0 * bflo(u0); acc.y += w0 * bfhi(u0);
        }
        unsigned uv = *reinterpret_cast<const unsigned*>(H + (size_t)node * 128 + col);
        float self = isq * isq;
        float ox = acc.x * isq + self * bflo(uv) + bias[col];
        float oy = acc.y * isq + self * bfhi(uv) + bias[col + 1];
        As[li][col]     = fmaxf(ox, 0.f);
        As[li][col + 1] = fmaxf(oy, 0.f);
    }
    __syncthreads();
    constexpr int COLT = NOUT / 4;
    int ct = tid % COLT;
    int r  = tid / COLT;          // [0, NODES)
    int c  = ct * 4;
    float4 acc = make_float4(0.f, 0.f, 0.f, 0.f);
    #pragma unroll 8
    for (int k = 0; k < 128; ++k) {
        float xv = As[r][k];
        float4 w = *reinterpret_cast<const float4*>(W + (size_t)k * NOUT + c);
        acc.x += xv * w.x; acc.y += xv * w.y; acc.z += xv * w.z; acc.w += xv * w.w;
    }
    int gr = blockIdx.x * NODES + r;
    ushort4 o;
    o.x = f2bf(acc.x); o.y = f2bf(acc.y); o.z = f2bf(acc.z); o.w = f2bf(acc.w);
    *reinterpret_cast<ushort4*>(Y + (size_t)gr * NOUT + c) = o;
}

// final: out = agg(H) + bias (f32, no relu). H: [NN][64] bf16. 4 nodes/block.
__global__ __launch_bounds__(256) void agg_final_kernel(
        const unsigned short* __restrict__ H, const int* __restrict__ esrc,
        const int* __restrict__ offs, const float* __restrict__ inv_sqrt,
        const float* __restrict__ bias, float* __restrict__ out) {
    int lane = threadIdx.x & 63, wv = threadIdx.x >> 6;
    int node = blockIdx.x * 4 + wv;
    int s = offs[node], e = offs[node + 1];
    float isq = inv_sqrt[node];
    float acc = 0.f;
    int j = s;
    for (; j + 4 <= e; j += 4) {
        int s0 = esrc[j], s1 = esrc[j + 1], s2 = esrc[j + 2], s3 = esrc[j + 3];
        float w0 = inv_sqrt[s0], w1 = inv_sqrt[s1];
        float w2 = inv_sqrt[s2], w3 = inv_sqrt[s3];
        acc += w0 * bf1(H[(size_t)s0 * 64 + lane]);
        acc += w1 * bf1(H[(size_t)s1 * 64 + lane]);
        acc += w2 * bf1(H[(size_t)s2 * 64 + lane]);
        acc += w3 * bf1(H[(size_t)s3 * 64 + lane]);
    }
    for (; j < e; ++j) {
        int s0 = esrc[j];
        acc += inv_sqrt[s0] * bf1(H[(size_t)s0 * 64 + lane]);
    }
    float hv = bf1(H[(size_t)node * 64 + lane]);
    out[(size_t)node * 64 + lane] = acc * isq + isq * isq * hv + bias[lane];
}

extern "C" void kernel_launch(void* const* d_in, const int* in_sizes, int n_in,
                              void* d_out, int out_size, void* d_ws, size_t ws_size,
                              hipStream_t stream) {
    const float* x  = (const float*)d_in[0];
    const int*   ei = (const int*)d_in[1];
    const float* W1 = (const float*)d_in[2];
    const float* b1 = (const float*)d_in[3];
    const float* W2 = (const float*)d_in[4];
    const float* b2 = (const float*)d_in[5];
    const float* W3 = (const float*)d_in[6];
    const float* b3 = (const float*)d_in[7];
    float* out = (float*)d_out;

    const int* src = ei;
    const int* dst = ei + NE;

    char* ws = (char*)d_ws;
    int*            bcur      = (int*)(ws);                        // 1,252 B
    float*          inv_sqrt  = (float*)(ws + 4096);               // 40,000 B
    int*            offs      = (int*)(ws + 45056);                // 40,004 B
    unsigned*       edge_part = (unsigned*)(ws + 86016);           // 3,365,376 B
    int*            edge_src  = (int*)(ws + 3451392);              // 2,560,000 B
    unsigned short* T1        = (unsigned short*)(ws + 6011392);   // 2,560,000 B
    unsigned short* T2        = (unsigned short*)(ws + 8571392);   // 2,560,000 B
    unsigned short* T3        = (unsigned short*)(ws + 11131392);  // 1,280,000 B

    zero_kernel<<<1, 320, 0, stream>>>(bcur);
    part_gemm1_kernel<<<NB + G1B, 256, 0, stream>>>(src, dst, bcur, edge_part, x, W1, T1);
    build_kernel<<<NB, 256, 0, stream>>>(edge_part, bcur, offs, inv_sqrt, edge_src);
    agg_gemm_kernel<128, 8><<<NN / 8, 256, 0, stream>>>(T1, edge_src, offs, inv_sqrt,
                                                        b1, W2, T2);
    agg_gemm_kernel<64, 16><<<NN / 16, 256, 0, stream>>>(T2, edge_src, offs, inv_sqrt,
                                                         b2, W3, T3);
    agg_final_kernel<<<NN / 4, 256, 0, stream>>>(T3, edge_src, offs, inv_sqrt, b3, out);
}

// Round 6
// 144.834 us; speedup vs baseline: 1.1063x; 1.1063x over previous
//
#include <hip/hip_runtime.h>

#define NN 10000
#define NE 640000
#define NB 313          // buckets of 32 nodes; also # partition blocks
#define RSTRIDE 2688    // slots per bucket (mean 2045, sigma~45)
#define EPB 2048        // edges per partition block
#define G1B 1250        // gemm1 blocks (10000/8)

__device__ __forceinline__ unsigned short f2bf(float x) {   // RNE
    unsigned u = __float_as_uint(x);
    u += 0x7FFFu + ((u >> 16) & 1u);
    return (unsigned short)(u >> 16);
}
__device__ __forceinline__ float bflo(unsigned u) { return __uint_as_float(u << 16); }
__device__ __forceinline__ float bfhi(unsigned u) { return __uint_as_float(u & 0xFFFF0000u); }
__device__ __forceinline__ float bf1(unsigned short h) { return __uint_as_float((unsigned)h << 16); }

// blocks [0,NB): partition edges into dst-buckets. rec = (dst<<14)|src.
// blocks [NB, NB+G1B): gemm1  T1[8 rows] = x[8x128] @ W1[128x128] -> bf16
__global__ __launch_bounds__(256) void part_gemm1_kernel(
        const int* __restrict__ src, const int* __restrict__ dst,
        int* __restrict__ bcur, unsigned* __restrict__ edge_part,
        const float* __restrict__ X, const float* __restrict__ W,
        unsigned short* __restrict__ Y) {
    __shared__ union SM {
        struct { int hist[NB]; int scanv[NB + 1]; int gbase[NB]; int lcur[NB];
                 unsigned stage[EPB]; } p;
        float xs[8][128];
    } sm;
    int tid = threadIdx.x;

    if (blockIdx.x >= NB) {                       // ---- gemm1 path ----
        int row0 = (blockIdx.x - NB) * 8;
        for (int idx = tid; idx < 8 * 128; idx += 256) {
            int r = idx >> 7, k = idx & 127;
            sm.xs[r][k] = X[(size_t)(row0 + r) * 128 + k];
        }
        __syncthreads();
        int ct = tid & 31, r = tid >> 5, c = ct * 4;
        float4 acc = make_float4(0.f, 0.f, 0.f, 0.f);
        #pragma unroll 8
        for (int k = 0; k < 128; ++k) {
            float xv = sm.xs[r][k];
            float4 w = *reinterpret_cast<const float4*>(W + (size_t)k * 128 + c);
            acc.x += xv * w.x; acc.y += xv * w.y; acc.z += xv * w.z; acc.w += xv * w.w;
        }
        ushort4 o;
        o.x = f2bf(acc.x); o.y = f2bf(acc.y); o.z = f2bf(acc.z); o.w = f2bf(acc.w);
        *reinterpret_cast<ushort4*>(Y + (size_t)(row0 + r) * 128 + c) = o;
        return;
    }

    // ---- partition path ----
    for (int i = tid; i < NB; i += 256) sm.p.hist[i] = 0;
    __syncthreads();
    int gi = blockIdx.x * EPB + tid * 8;
    unsigned rec[8];
    bool act = gi < NE;
    if (act) {
        int4 s0 = *reinterpret_cast<const int4*>(src + gi);
        int4 s1 = *reinterpret_cast<const int4*>(src + gi + 4);
        int4 d0 = *reinterpret_cast<const int4*>(dst + gi);
        int4 d1 = *reinterpret_cast<const int4*>(dst + gi + 4);
        rec[0] = ((unsigned)d0.x << 14) | (unsigned)s0.x;
        rec[1] = ((unsigned)d0.y << 14) | (unsigned)s0.y;
        rec[2] = ((unsigned)d0.z << 14) | (unsigned)s0.z;
        rec[3] = ((unsigned)d0.w << 14) | (unsigned)s0.w;
        rec[4] = ((unsigned)d1.x << 14) | (unsigned)s1.x;
        rec[5] = ((unsigned)d1.y << 14) | (unsigned)s1.y;
        rec[6] = ((unsigned)d1.z << 14) | (unsigned)s1.z;
        rec[7] = ((unsigned)d1.w << 14) | (unsigned)s1.w;
        #pragma unroll
        for (int k = 0; k < 8; ++k) atomicAdd(&sm.p.hist[rec[k] >> 19], 1);
    }
    __syncthreads();
    if (tid < 64) {          // wave-0 exclusive scan of hist
        int carry = 0;
        for (int c = 0; c < NB; c += 64) {
            int idx = c + tid;
            int v = (idx < NB) ? sm.p.hist[idx] : 0;
            int incl = v;
            #pragma unroll
            for (int d = 1; d < 64; d <<= 1) {
                int t = __shfl_up(incl, d, 64);
                if (tid >= d) incl += t;
            }
            if (idx < NB) sm.p.scanv[idx] = carry + incl - v;
            carry += __shfl(incl, 63, 64);
        }
        if (tid == 0) sm.p.scanv[NB] = carry;
    }
    __syncthreads();
    for (int b = tid; b < NB; b += 256) {
        sm.p.gbase[b] = atomicAdd(&bcur[b], sm.p.hist[b]);
        sm.p.lcur[b]  = sm.p.scanv[b];
    }
    __syncthreads();
    if (act) {
        #pragma unroll
        for (int k = 0; k < 8; ++k) {
            int b = rec[k] >> 19;
            int p = atomicAdd(&sm.p.lcur[b], 1);
            sm.p.stage[p] = rec[k];
        }
    }
    __syncthreads();
    int tot = sm.p.scanv[NB];
    for (int i = tid; i < tot; i += 256) {
        unsigned r = sm.p.stage[i];
        int b = r >> 19;
        edge_part[b * RSTRIDE + sm.p.gbase[b] + (i - sm.p.scanv[b])] = r;
    }
}

// per bucket: scan totals -> base; degrees -> inv_sqrt/offs; group by node; CSR write
__global__ __launch_bounds__(256) void build_kernel(const unsigned* __restrict__ edge_part,
                                                    const int* __restrict__ bcur,
                                                    int* __restrict__ offs,
                                                    float* __restrict__ inv_sqrt,
                                                    int* __restrict__ edge_src) {
    __shared__ int sbase[NB + 1];
    __shared__ int hist32[32];
    __shared__ int cur32[32];
    __shared__ unsigned stage[RSTRIDE];
    int tid = threadIdx.x;
    if (tid < 64) {
        int carry = 0;
        for (int c = 0; c < NB; c += 64) {
            int idx = c + tid;
            int v = (idx < NB) ? bcur[idx] : 0;
            int incl = v;
            #pragma unroll
            for (int d = 1; d < 64; d <<= 1) {
                int t = __shfl_up(incl, d, 64);
                if (tid >= d) incl += t;
            }
            if (idx < NB) sbase[idx] = carry + incl - v;
            carry += __shfl(incl, 63, 64);
        }
    }
    if (tid < 32) hist32[tid] = 0;
    __syncthreads();
    int b = blockIdx.x;
    int cnt = bcur[b];
    int base = sbase[b];
    const unsigned* part = edge_part + (size_t)b * RSTRIDE;
    for (int k = tid; k < cnt; k += 256)
        atomicAdd(&hist32[(part[k] >> 14) & 31], 1);
    __syncthreads();
    if (tid < 32) {
        int v = hist32[tid];
        int incl = v;
        #pragma unroll
        for (int d = 1; d < 32; d <<= 1) {
            int t = __shfl_up(incl, d, 32);
            if (tid >= d) incl += t;
        }
        int excl = incl - v;
        cur32[tid] = excl;
        int node = b * 32 + tid;
        if (node < NN) {
            offs[node] = base + excl;
            inv_sqrt[node] = rsqrtf((float)(v + 1));
        }
        if (b == NB - 1 && tid == 0) offs[NN] = base + cnt;
    }
    __syncthreads();
    for (int k = tid; k < cnt; k += 256) {
        unsigned r = part[k];
        int p = atomicAdd(&cur32[(r >> 14) & 31], 1);
        stage[p] = r & 0x3FFFu;
    }
    __syncthreads();
    for (int k = tid; k < cnt; k += 256)
        edge_src[base + k] = (int)stage[k];
}

// 128-ch aggregation, 2 waves per node (each takes half the edge list), bf16 out.
// out = relu(isq*sum + isq^2*H[node] + bias)
__global__ __launch_bounds__(128) void agg128_kernel(
        const unsigned short* __restrict__ H, const int* __restrict__ esrc,
        const int* __restrict__ offs, const float* __restrict__ inv_sqrt,
        const float* __restrict__ bias, unsigned* __restrict__ Aout) {
    __shared__ float2 red[64];
    int node = blockIdx.x;
    int tid = threadIdx.x, lane = tid & 63, wv = tid >> 6;
    int s = offs[node], e = offs[node + 1];
    int deg = e - s;
    int half = ((deg >> 1) + 3) & ~3;       // multiple of 4
    int js = s + wv * half;
    int mid = s + half;
    int je = wv ? e : (mid < e ? mid : e);
    int col = lane * 2;
    float2 acc = make_float2(0.f, 0.f);
    int j = js;
    for (; j + 4 <= je; j += 4) {
        int s0 = esrc[j], s1 = esrc[j + 1], s2 = esrc[j + 2], s3 = esrc[j + 3];
        float w0 = inv_sqrt[s0], w1 = inv_sqrt[s1];
        float w2 = inv_sqrt[s2], w3 = inv_sqrt[s3];
        unsigned u0 = *reinterpret_cast<const unsigned*>(H + (size_t)s0 * 128 + col);
        unsigned u1 = *reinterpret_cast<const unsigned*>(H + (size_t)s1 * 128 + col);
        unsigned u2 = *reinterpret_cast<const unsigned*>(H + (size_t)s2 * 128 + col);
        unsigned u3 = *reinterpret_cast<const unsigned*>(H + (size_t)s3 * 128 + col);
        acc.x += w0 * bflo(u0); acc.y += w0 * bfhi(u0);
        acc.x += w1 * bflo(u1); acc.y += w1 * bfhi(u1);
        acc.x += w2 * bflo(u2); acc.y += w2 * bfhi(u2);
        acc.x += w3 * bflo(u3); acc.y += w3 * bfhi(u3);
    }
    for (; j < je; ++j) {
        int s0 = esrc[j];
        float w0 = inv_sqrt[s0];
        unsigned u0 = *reinterpret_cast<const unsigned*>(H + (size_t)s0 * 128 + col);
        acc.x += w0 * bflo(u0); acc.y += w0 * bfhi(u0);
    }
    if (wv) red[lane] = acc;
    __syncthreads();
    if (!wv) {
        acc.x += red[lane].x; acc.y += red[lane].y;
        float isq = inv_sqrt[node];
        unsigned uv = *reinterpret_cast<const unsigned*>(H + (size_t)node * 128 + col);
        float self = isq * isq;
        float ox = fmaxf(acc.x * isq + self * bflo(uv) + bias[col], 0.f);
        float oy = fmaxf(acc.y * isq + self * bfhi(uv) + bias[col + 1], 0.f);
        Aout[(size_t)node * 64 + lane] = (unsigned)f2bf(ox) | ((unsigned)f2bf(oy) << 16);
    }
}

// 64-ch final aggregation, 2 waves per node, f32 out, no relu
__global__ __launch_bounds__(128) void agg64_kernel(
        const unsigned short* __restrict__ H, const int* __restrict__ esrc,
        const int* __restrict__ offs, const float* __restrict__ inv_sqrt,
        const float* __restrict__ bias, float* __restrict__ out) {
    __shared__ float red[64];
    int node = blockIdx.x;
    int tid = threadIdx.x, lane = tid & 63, wv = tid >> 6;
    int s = offs[node], e = offs[node + 1];
    int deg = e - s;
    int half = ((deg >> 1) + 3) & ~3;
    int js = s + wv * half;
    int mid = s + half;
    int je = wv ? e : (mid < e ? mid : e);
    float acc = 0.f;
    int j = js;
    for (; j + 4 <= je; j += 4) {
        int s0 = esrc[j], s1 = esrc[j + 1], s2 = esrc[j + 2], s3 = esrc[j + 3];
        float w0 = inv_sqrt[s0], w1 = inv_sqrt[s1];
        float w2 = inv_sqrt[s2], w3 = inv_sqrt[s3];
        acc += w0 * bf1(H[(size_t)s0 * 64 + lane]);
        acc += w1 * bf1(H[(size_t)s1 * 64 + lane]);
        acc += w2 * bf1(H[(size_t)s2 * 64 + lane]);
        acc += w3 * bf1(H[(size_t)s3 * 64 + lane]);
    }
    for (; j < je; ++j) {
        int s0 = esrc[j];
        acc += inv_sqrt[s0] * bf1(H[(size_t)s0 * 64 + lane]);
    }
    if (wv) red[lane] = acc;
    __syncthreads();
    if (!wv) {
        acc += red[lane];
        float isq = inv_sqrt[node];
        float hv = bf1(H[(size_t)node * 64 + lane]);
        out[(size_t)node * 64 + lane] = acc * isq + isq * isq * hv + bias[lane];
    }
}

// Y[.,N] (bf16) = X[.,128] (bf16) @ W[128,N] (f32)
template<int N>
__global__ __launch_bounds__(256) void gemm_bf_kernel(const unsigned short* __restrict__ X,
                                                      const float* __restrict__ W,
                                                      unsigned short* __restrict__ Y) {
    constexpr int COLT = N / 4;
    constexpr int ROWS = 256 / COLT;
    __shared__ float Xs[ROWS][128];
    int tid = threadIdx.x;
    int row0 = blockIdx.x * ROWS;
    const unsigned* Xu = reinterpret_cast<const unsigned*>(X + (size_t)row0 * 128);
    for (int idx = tid; idx < ROWS * 64; idx += 256) {
        unsigned u = Xu[idx];
        int r = idx >> 6, kk = idx & 63;
        Xs[r][kk * 2]     = bflo(u);
        Xs[r][kk * 2 + 1] = bfhi(u);
    }
    __syncthreads();
    int ct = tid % COLT;
    int r  = tid / COLT;
    int c  = ct * 4;
    float4 acc = make_float4(0.f, 0.f, 0.f, 0.f);
    #pragma unroll 8
    for (int k = 0; k < 128; ++k) {
        float xv = Xs[r][k];
        float4 w = *reinterpret_cast<const float4*>(W + (size_t)k * N + c);
        acc.x += xv * w.x; acc.y += xv * w.y; acc.z += xv * w.z; acc.w += xv * w.w;
    }
    ushort4 o;
    o.x = f2bf(acc.x); o.y = f2bf(acc.y); o.z = f2bf(acc.z); o.w = f2bf(acc.w);
    *reinterpret_cast<ushort4*>(Y + (size_t)(row0 + r) * N + c) = o;
}

extern "C" void kernel_launch(void* const* d_in, const int* in_sizes, int n_in,
                              void* d_out, int out_size, void* d_ws, size_t ws_size,
                              hipStream_t stream) {
    const float* x  = (const float*)d_in[0];
    const int*   ei = (const int*)d_in[1];
    const float* W1 = (const float*)d_in[2];
    const float* b1 = (const float*)d_in[3];
    const float* W2 = (const float*)d_in[4];
    const float* b2 = (const float*)d_in[5];
    const float* W3 = (const float*)d_in[6];
    const float* b3 = (const float*)d_in[7];
    float* out = (float*)d_out;

    const int* src = ei;
    const int* dst = ei + NE;

    char* ws = (char*)d_ws;
    int*            bcur      = (int*)(ws);                        // 1,252 B
    float*          inv_sqrt  = (float*)(ws + 4096);               // 40,000 B
    int*            offs      = (int*)(ws + 45056);                // 40,004 B
    unsigned*       edge_part = (unsigned*)(ws + 86016);           // 3,365,376 B
    int*            edge_src  = (int*)(ws + 3451392);              // 2,560,000 B
    unsigned short* T1        = (unsigned short*)(ws + 6011392);   // 2,560,000 B
    unsigned short* A         = (unsigned short*)(ws + 8571392);   // 2,560,000 B
    unsigned short* T2        = (unsigned short*)edge_part;        // alias (dead after build)
    unsigned short* T3        = T1;                                // alias (dead after agg1)

    hipMemsetAsync(bcur, 0, NB * sizeof(int), stream);
    part_gemm1_kernel<<<NB + G1B, 256, 0, stream>>>(src, dst, bcur, edge_part, x, W1, T1);
    build_kernel<<<NB, 256, 0, stream>>>(edge_part, bcur, offs, inv_sqrt, edge_src);

    agg128_kernel<<<NN, 128, 0, stream>>>(T1, edge_src, offs, inv_sqrt, b1, (unsigned*)A);
    gemm_bf_kernel<128><<<NN / 8, 256, 0, stream>>>(A, W2, T2);
    agg128_kernel<<<NN, 128, 0, stream>>>(T2, edge_src, offs, inv_sqrt, b2, (unsigned*)A);
    gemm_bf_kernel<64><<<NN / 16, 256, 0, stream>>>(A, W3, T3);
    agg64_kernel<<<NN, 128, 0, stream>>>(T3, edge_src, offs, inv_sqrt, b3, out);
}